// Round 17
// baseline (123.067 us; speedup 1.0000x reference)
//
#include <hip/hip_runtime.h>
#include <hip/hip_bf16.h>

#define BATCH 32
#define CIN   256
#define COUT  256
#define Hd    56
#define Wd    56
#define HW    (Hd*Wd)

typedef __attribute__((ext_vector_type(8))) short bf16x8;
typedef __attribute__((ext_vector_type(4))) float f32x4;

typedef const __attribute__((address_space(1))) void* gas1_t;
typedef __attribute__((address_space(3))) void* las3_t;

__device__ __forceinline__ unsigned short f2bf_rne(float f) {
    unsigned u = __builtin_bit_cast(unsigned, f);
    u += 0x7fffu + ((u >> 16) & 1u);
    return (unsigned short)(u >> 16);
}

// ---------------------------------------------------------------------------
// Fused prep: blocks [0,1856) xconv | [1856,1904) wprep | [1904,1936) bsum.
// xconv (R7-verified residue-interleaved layout, R16-vectorized):
//   xb[b][p 4][row 58 (0,57 zero)][col 64 (56-63 zero)][64ch bf16,
//   octet-XOR-swizzled by col&7]; pass p, kq = oct*8+e, rr = kq>>4,
//   jj = kq&15, ic = (p*16+jj)*4+rr.
// wprep: lane-linear 1 KB chunks (R9 trick, re-indexed):
//   Wc chunk u = r*32+p*8+ks*4+mf : e -> kq = ks*32+l4*8+e, ic as above.
//   Wg chunk u2 = r*64+p*16+tp*4+mf : t8 = tp*2+(l4>>1), jj = (l4&1)*8+e,
//   ic = (p*16+jj)*4+r, tap = t8+(t8>=4).
// ---------------------------------------------------------------------------
__global__ __launch_bounds__(512) void hetconv_prep_all(const float* __restrict__ x,
                                                        const float* __restrict__ W,
                                                        const float* __restrict__ bb_,
                                                        unsigned short* __restrict__ xb,
                                                        unsigned short* __restrict__ Wc3,
                                                        unsigned short* __restrict__ Wg3,
                                                        float* __restrict__ bsum) {
    const int bid = blockIdx.x;
    const int tid = threadIdx.x;
    const int lane = tid & 63;
    const int wid  = tid >> 6;

    if (bid < 1856) {                    // ---- xconv ----
        const int b  = bid / 58;
        const int pr = bid % 58;
        const int octG = tid >> 4;       // [0,32)
        const int q    = tid & 15;       // col quad; 14,15 write zeros
        const int pass = octG >> 3;      // residue-interleaved pass
        const int oct  = octG & 7;
        const int grow = pr - 1;
        const bool ok = (grow >= 0) && (grow < Hd) && (q < 14);
        const size_t base = ((size_t)(b * 4 + pass) * 58 + pr) * 4096;
        const float* xrow = x + (size_t)b * CIN * HW + (size_t)grow * Wd + q * 4;

        f32x4 v[8];
        #pragma unroll
        for (int e = 0; e < 8; ++e) {
            int kq = oct * 8 + e;
            int rr = kq >> 4, jj = kq & 15;
            int ic = (pass * 16 + jj) * 4 + rr;
            v[e] = ok ? *reinterpret_cast<const f32x4*>(xrow + (size_t)ic * HW)
                      : f32x4{0.f, 0.f, 0.f, 0.f};
        }
        #pragma unroll
        for (int i = 0; i < 4; ++i) {
            int col = q * 4 + i;
            bf16x8 pk;
            #pragma unroll
            for (int e = 0; e < 8; ++e) pk[e] = (short)f2bf_rne(v[e][i]);
            __builtin_nontemporal_store(pk,
                reinterpret_cast<bf16x8*>(xb + base + col * 64 + ((oct ^ (col & 7)) * 8)));
        }
    } else if (bid < 1904) {             // ---- wprep: 8 chunks per block ----
        const int u = (bid - 1856) * 8 + wid;    // [0,384)
        const int l15 = lane & 15;
        const int l4  = lane >> 4;
        if (u < 128) {                   // Wc: u = r*32+p*8+ks*4+mf
            const int mf = u & 3;
            const int ks = (u >> 2) & 1;
            const int p  = (u >> 3) & 3;
            const int r  = u >> 5;
            const int np = r * 64 + mf * 16 + l15;
            const int n  = ((np & 63) << 2) | r;
            #pragma unroll
            for (int e = 0; e < 8; ++e) {
                int kq = ks * 32 + l4 * 8 + e;
                int rr = kq >> 4, jj = kq & 15;
                int ic = (p * 16 + jj) * 4 + rr;
                Wc3[u * 512 + lane * 8 + e] = f2bf_rne(W[(n * CIN + ic) * 9 + 4]);
            }
        } else {                         // Wg: u2 = r*64+p*16+tp*4+mf
            const int u2 = u - 128;
            const int mf = u2 & 3;
            const int tp = (u2 >> 2) & 3;
            const int p  = (u2 >> 4) & 3;
            const int r  = u2 >> 6;
            const int np = r * 64 + mf * 16 + l15;
            const int n  = ((np & 63) << 2) | r;
            const int t8  = tp * 2 + (l4 >> 1);
            const int tap = t8 + (t8 >= 4);
            #pragma unroll
            for (int e = 0; e < 8; ++e) {
                int jj = (l4 & 1) * 8 + e;
                int ic = (p * 16 + jj) * 4 + r;
                Wg3[u2 * 512 + lane * 8 + e] = f2bf_rne(W[(n * CIN + ic) * 9 + tap]);
            }
        }
    } else {                             // ---- bsum: 8 np per block ----
        const int np = (bid - 1904) * 8 + wid;   // [0,256)
        const int n = ((np & 63) << 2) | (np >> 6);
        float s = 0.f;
        for (int i = lane; i < CIN; i += 64) s += bb_[n * CIN + i];
        #pragma unroll
        for (int off = 32; off > 0; off >>= 1) s += __shfl_down(s, off, 64);
        if (lane == 0) bsum[np] = s;
    }
}

// ---------------------------------------------------------------------------
// Main: 896 blocks (XCD-swizzled) x 512 threads = 8 waves = (h = wid&1,
// r = wid>>1); per-wave 64 out-ch x 64 cols, acc[4][4] = 64 AGPR (+~60 arch).
// LDS = 32 KB slab + 29.7 KB scratch = 62.5 KB -> 2 blocks/CU: sibling block
// overlaps this block's stage-drain and epilogue.  4 residue-interleaved
// passes of 64 ch; EVERY pass EVERY wave: 32 dense + 64 grouped (tap-pair
// K=32, R7-verified lane mapping) MFMA -> balanced barriers.
// ---------------------------------------------------------------------------
__global__ __launch_bounds__(512, 2) void hetconv_main(const unsigned short* __restrict__ xb,
                             const unsigned short* __restrict__ Wc3,
                             const unsigned short* __restrict__ Wg3,
                             const float* __restrict__ bsum,
                             float* __restrict__ y) {
    __shared__ unsigned short xs[16384];      // 32 KB pass slab
    __shared__ float lf2[64 * 116];           // 29,696 B epilogue scratch

    const int bid  = blockIdx.x;
    const int work = (bid & 7) * 112 + (bid >> 3);   // XCD-contiguous (896 = 8*112)
    const int b    = work / 28;
    const int R0   = (work % 28) * 2;
    const int tid = threadIdx.x;
    const int lane = tid & 63;
    const int wid  = tid >> 6;        // [0,8)
    const int h = wid & 1;
    const int r = wid >> 1;
    const int l15 = lane & 15;
    const int l4  = lane >> 4;

    f32x4 acc[4][4];
    #pragma unroll
    for (int i = 0; i < 4; ++i)
        #pragma unroll
        for (int j = 0; j < 4; ++j) acc[i][j] = f32x4{0.f, 0.f, 0.f, 0.f};

    auto STAGE = [&](int p) {       // 32 KB slab: 4 rows x 64 col x 64 ch
        const unsigned short* slab = xb + ((size_t)(b * 4 + p) * 58 + R0) * 4096;
        #pragma unroll
        for (int i = 0; i < 4; ++i) {
            int vbase = (wid * 4 + i) * 64;           // 16B units, wave-uniform
            __builtin_amdgcn_global_load_lds(
                (gas1_t)(slab + (size_t)(vbase + lane) * 8),
                (las3_t)(xs + vbase * 8), 16, 0, 0);
        }
    };

    STAGE(0);
    asm volatile("s_waitcnt vmcnt(0)" ::: "memory");
    __builtin_amdgcn_s_barrier();

    #pragma unroll
    for (int p = 0; p < 4; ++p) {
        // ---- dense: 2 K-steps of 32 interleaved channels ----
        {
            const int srow = (h + 1) * 64;
            #pragma unroll
            for (int ks = 0; ks < 2; ++ks) {
                bf16x8 a[4];
                #pragma unroll
                for (int mf = 0; mf < 4; ++mf) {
                    int chunk = r * 32 + p * 8 + ks * 4 + mf;
                    a[mf] = *reinterpret_cast<const bf16x8*>(
                        Wc3 + ((size_t)chunk << 9) + lane * 8);
                }
                #pragma unroll
                for (int nf = 0; nf < 4; ++nf) {
                    int col = nf * 16 + l15;
                    int pix = srow + col;
                    int oct = ks * 4 + l4;
                    int addr = pix * 128 + ((oct ^ (col & 7)) << 4);
                    bf16x8 bbv = *reinterpret_cast<const bf16x8*>(
                        reinterpret_cast<const char*>(xs) + addr);
                    #pragma unroll
                    for (int mf = 0; mf < 4; ++mf)
                        acc[mf][nf] = __builtin_amdgcn_mfma_f32_16x16x32_bf16(
                            a[mf], bbv, acc[mf][nf], 0, 0, 0);
                }
            }
        }

        // ---- grouped: 4 tap-pairs (K=32: lanes l4<2 tap a, l4>=2 tap b) ----
        #pragma unroll
        for (int tp = 0; tp < 4; ++tp) {
            const int t8  = tp * 2 + (l4 >> 1);       // per-lane tap
            const int tap = t8 + (t8 >= 4);
            const int dy  = tap / 3 - 1;
            const int dx  = tap % 3 - 1;
            const int lr  = h + 1 + dy;
            const int oct = r * 2 + (l4 & 1);
            bf16x8 ag[4];
            #pragma unroll
            for (int mf = 0; mf < 4; ++mf) {
                int chunk = r * 64 + p * 16 + tp * 4 + mf;
                ag[mf] = *reinterpret_cast<const bf16x8*>(
                    Wg3 + ((size_t)chunk << 9) + lane * 8);
            }
            #pragma unroll
            for (int nf = 0; nf < 4; ++nf) {
                int c2 = nf * 16 + l15 + dx;
                c2 = ((unsigned)c2 < 64u) ? c2 : 56;   // col 56 is zero pad
                int pix  = lr * 64 + c2;
                int addr = pix * 128 + ((oct ^ (c2 & 7)) << 4);
                bf16x8 bbv = *reinterpret_cast<const bf16x8*>(
                    reinterpret_cast<const char*>(xs) + addr);
                #pragma unroll
                for (int mf = 0; mf < 4; ++mf)
                    acc[mf][nf] = __builtin_amdgcn_mfma_f32_16x16x32_bf16(
                        ag[mf], bbv, acc[mf][nf], 0, 0, 0);
            }
        }

        __syncthreads();                 // slab reads done
        if (p < 3) {
            STAGE(p + 1);
            asm volatile("s_waitcnt vmcnt(0)" ::: "memory");
            __builtin_amdgcn_s_barrier();
        }
    }

    // ---- epilogue: 4 residue-rounds via lf2, coalesced f32x4 stores ----
    #pragma unroll
    for (int q = 0; q < 4; ++q) {
        if (r == q) {
            #pragma unroll
            for (int mf = 0; mf < 4; ++mf) {
                #pragma unroll
                for (int j = 0; j < 4; ++j) {
                    int npl = mf * 16 + l4 * 4 + j;   // [0,64)
                    float bias = bsum[q * 64 + npl];
                    #pragma unroll
                    for (int nf = 0; nf < 4; ++nf) {
                        int col = nf * 16 + l15;
                        if (col < Wd)
                            lf2[npl * 116 + h * 56 + col] = acc[mf][nf][j] + bias;
                    }
                }
            }
        }
        __syncthreads();
        #pragma unroll
        for (int it = 0; it < 4; ++it) {
            int v = it * 512 + tid;            // 64 npl x 28 float4
            if (v < 1792) {
                int npl = v / 28;
                int f   = v % 28;
                int h2  = (f >= 14) ? 1 : 0;
                int colS = (f - h2 * 14) * 4;
                int n = (npl << 2) | q;
                f32x4 val = *reinterpret_cast<const f32x4*>(lf2 + npl * 116 + f * 4);
                __builtin_nontemporal_store(val, reinterpret_cast<f32x4*>(
                    y + (((size_t)b * COUT + n) * Hd + (R0 + h2)) * Wd + colS));
            }
        }
        __syncthreads();
    }
}

extern "C" void kernel_launch(void* const* d_in, const int* in_sizes, int n_in,
                              void* d_out, int out_size, void* d_ws, size_t ws_size,
                              hipStream_t stream) {
    const float* x = (const float*)d_in[0];
    const float* W = (const float*)d_in[1];
    const float* b = (const float*)d_in[2];
    float* y = (float*)d_out;

    unsigned short* Wc3  = (unsigned short*)d_ws;                        // 131072 B
    unsigned short* Wg3  = (unsigned short*)((char*)d_ws + 131072);      // 262144 B
    float*          bsum = (float*)((char*)d_ws + 393216);               // 1024 B
    unsigned short* xb   = (unsigned short*)((char*)d_ws + 394240);      // 60,817,408 B

    hipLaunchKernelGGL(hetconv_prep_all, dim3(1936), dim3(512), 0, stream,
                       x, W, b, xb, Wc3, Wg3, bsum);
    hipLaunchKernelGGL(hetconv_main, dim3(BATCH * 28), dim3(512), 0, stream,
                       xb, Wc3, Wg3, bsum, y);
}

// Round 18
// 116.316 us; speedup vs baseline: 1.0580x; 1.0580x over previous
//
#include <hip/hip_runtime.h>
#include <hip/hip_bf16.h>

#define BATCH 32
#define CIN   256
#define COUT  256
#define Hd    56
#define Wd    56
#define HW    (Hd*Wd)

typedef __attribute__((ext_vector_type(8))) short bf16x8;
typedef __attribute__((ext_vector_type(4))) float f32x4;

typedef const __attribute__((address_space(1))) void* gas1_t;
typedef __attribute__((address_space(3))) void* las3_t;

__device__ __forceinline__ unsigned short f2bf_rne(float f) {
    unsigned u = __builtin_bit_cast(unsigned, f);
    u += 0x7fffu + ((u >> 16) & 1u);
    return (unsigned short)(u >> 16);
}

// ---------------------------------------------------------------------------
// Fused prep (R17-verified, unchanged): [0,1856) xconv | [1856,1904) wprep |
// [1904,1936) bsum.  xb[b][p 4][row 58][col 64][64ch, octet-XOR by col&7],
// residue-interleaved: ic = (p*16+jj)*4+rr for kq = oct*8+e, rr=kq>>4,
// jj=kq&15.  Weight chunks lane-linear 1 KB.
// ---------------------------------------------------------------------------
__global__ __launch_bounds__(512) void hetconv_prep_all(const float* __restrict__ x,
                                                        const float* __restrict__ W,
                                                        const float* __restrict__ bb_,
                                                        unsigned short* __restrict__ xb,
                                                        unsigned short* __restrict__ Wc3,
                                                        unsigned short* __restrict__ Wg3,
                                                        float* __restrict__ bsum) {
    const int bid = blockIdx.x;
    const int tid = threadIdx.x;
    const int lane = tid & 63;
    const int wid  = tid >> 6;

    if (bid < 1856) {                    // ---- xconv ----
        const int b  = bid / 58;
        const int pr = bid % 58;
        const int octG = tid >> 4;       // [0,32)
        const int q    = tid & 15;       // col quad; 14,15 write zeros
        const int pass = octG >> 3;
        const int oct  = octG & 7;
        const int grow = pr - 1;
        const bool ok = (grow >= 0) && (grow < Hd) && (q < 14);
        const size_t base = ((size_t)(b * 4 + pass) * 58 + pr) * 4096;
        const float* xrow = x + (size_t)b * CIN * HW + (size_t)grow * Wd + q * 4;

        f32x4 v[8];
        #pragma unroll
        for (int e = 0; e < 8; ++e) {
            int kq = oct * 8 + e;
            int rr = kq >> 4, jj = kq & 15;
            int ic = (pass * 16 + jj) * 4 + rr;
            v[e] = ok ? *reinterpret_cast<const f32x4*>(xrow + (size_t)ic * HW)
                      : f32x4{0.f, 0.f, 0.f, 0.f};
        }
        #pragma unroll
        for (int i = 0; i < 4; ++i) {
            int col = q * 4 + i;
            bf16x8 pk;
            #pragma unroll
            for (int e = 0; e < 8; ++e) pk[e] = (short)f2bf_rne(v[e][i]);
            __builtin_nontemporal_store(pk,
                reinterpret_cast<bf16x8*>(xb + base + col * 64 + ((oct ^ (col & 7)) * 8)));
        }
    } else if (bid < 1904) {             // ---- wprep ----
        const int u = (bid - 1856) * 8 + wid;    // [0,384)
        const int l15 = lane & 15;
        const int l4  = lane >> 4;
        if (u < 128) {                   // Wc: u = r*32+p*8+ks*4+mf
            const int mf = u & 3;
            const int ks = (u >> 2) & 1;
            const int p  = (u >> 3) & 3;
            const int r  = u >> 5;
            const int np = r * 64 + mf * 16 + l15;
            const int n  = ((np & 63) << 2) | r;
            #pragma unroll
            for (int e = 0; e < 8; ++e) {
                int kq = ks * 32 + l4 * 8 + e;
                int rr = kq >> 4, jj = kq & 15;
                int ic = (p * 16 + jj) * 4 + rr;
                Wc3[u * 512 + lane * 8 + e] = f2bf_rne(W[(n * CIN + ic) * 9 + 4]);
            }
        } else {                         // Wg: u2 = r*64+p*16+tp*4+mf
            const int u2 = u - 128;
            const int mf = u2 & 3;
            const int tp = (u2 >> 2) & 3;
            const int p  = (u2 >> 4) & 3;
            const int r  = u2 >> 6;
            const int np = r * 64 + mf * 16 + l15;
            const int n  = ((np & 63) << 2) | r;
            const int t8  = tp * 2 + (l4 >> 1);
            const int tap = t8 + (t8 >= 4);
            #pragma unroll
            for (int e = 0; e < 8; ++e) {
                int jj = (l4 & 1) * 8 + e;
                int ic = (p * 16 + jj) * 4 + r;
                Wg3[u2 * 512 + lane * 8 + e] = f2bf_rne(W[(n * CIN + ic) * 9 + tap]);
            }
        }
    } else {                             // ---- bsum ----
        const int np = (bid - 1904) * 8 + wid;   // [0,256)
        const int n = ((np & 63) << 2) | (np >> 6);
        float s = 0.f;
        for (int i = lane; i < CIN; i += 64) s += bb_[n * CIN + i];
        #pragma unroll
        for (int off = 32; off > 0; off >>= 1) s += __shfl_down(s, off, 64);
        if (lane == 0) bsum[np] = s;
    }
}

// ---------------------------------------------------------------------------
// Main: 1792 blocks (XCD-swizzled, 8x224) = (batch, single output row).
// 512 threads = 8 waves = (mh = wid&1, r = wid>>1); per-wave 32 out-ch x
// 56 cols, acc[2][4] = 32 AGPR + ~56 arch = 88 unified -> TWO blocks/CU
// (16 waves, 2x88x16=1408 <= 2048 regs; 2 x 63 KB LDS <= 160 KB): the
// sibling block's MFMA stream hides this block's stage-drains and epilogue.
// 4 residue-interleaved passes of 64 ch from double-buffered 3-row slabs
// (24.5 KB); dense af hoisted before next-slab stage issue; R17-verified
// tap-pair grouped math.  Epilogue: 4 residue-rounds via 15 KB scratch.
// ---------------------------------------------------------------------------
__global__ __launch_bounds__(512, 2) void hetconv_main(const unsigned short* __restrict__ xb,
                             const unsigned short* __restrict__ Wc3,
                             const unsigned short* __restrict__ Wg3,
                             const float* __restrict__ bsum,
                             float* __restrict__ y) {
    __shared__ unsigned short xs[2][12288];   // 2 x 24,576 B slabs (3 rows)
    __shared__ float lf2[64 * 60];            // 15,360 B epilogue scratch

    const int bid  = blockIdx.x;
    const int work = (bid & 7) * 224 + (bid >> 3);   // 1792 = 8*224
    const int b    = work / 56;
    const int row  = work % 56;
    const int tid = threadIdx.x;
    const int lane = tid & 63;
    const int wid  = tid >> 6;        // [0,8)
    const int mh = wid & 1;
    const int r  = wid >> 1;
    const int l15 = lane & 15;
    const int l4  = lane >> 4;

    f32x4 acc[2][4];
    #pragma unroll
    for (int i = 0; i < 2; ++i)
        #pragma unroll
        for (int j = 0; j < 4; ++j) acc[i][j] = f32x4{0.f, 0.f, 0.f, 0.f};

    // slab rows = padded rows row..row+2 (= image rows row-1..row+1)
    auto STAGE = [&](int p, unsigned short* dst) {
        const unsigned short* slab = xb + ((size_t)(b * 4 + p) * 58 + row) * 4096;
        #pragma unroll
        for (int i = 0; i < 3; ++i) {
            int vbase = (wid * 3 + i) * 64;           // 16B units, wave-uniform
            __builtin_amdgcn_global_load_lds(
                (gas1_t)(slab + (size_t)(vbase + lane) * 8),
                (las3_t)(dst + vbase * 8), 16, 0, 0);
        }
    };

    STAGE(0, xs[0]);
    asm volatile("s_waitcnt vmcnt(0)" ::: "memory");
    __builtin_amdgcn_s_barrier();

    #pragma unroll
    for (int p = 0; p < 4; ++p) {
        const unsigned short* buf = xs[p & 1];

        // ---- dense A-frags hoisted BEFORE next-slab stage issue ----
        bf16x8 af[2][2];
        #pragma unroll
        for (int ks = 0; ks < 2; ++ks)
            #pragma unroll
            for (int mfl = 0; mfl < 2; ++mfl) {
                int chunk = r * 32 + p * 8 + ks * 4 + mh * 2 + mfl;
                af[ks][mfl] = *reinterpret_cast<const bf16x8*>(
                    Wc3 + ((size_t)chunk << 9) + lane * 8);
            }
        __builtin_amdgcn_sched_barrier(0);
        if (p < 3) STAGE(p + 1, xs[(p + 1) & 1]);
        __builtin_amdgcn_sched_barrier(0);

        // ---- dense: 2 K-steps of 32 interleaved channels ----
        #pragma unroll
        for (int ks = 0; ks < 2; ++ks) {
            #pragma unroll
            for (int nf = 0; nf < 4; ++nf) {
                int col = nf * 16 + l15;
                int pix = 64 + col;                   // slab row 1 = image row
                int oct = ks * 4 + l4;
                int addr = pix * 128 + ((oct ^ (col & 7)) << 4);
                bf16x8 bbv = *reinterpret_cast<const bf16x8*>(
                    reinterpret_cast<const char*>(buf) + addr);
                #pragma unroll
                for (int mfl = 0; mfl < 2; ++mfl)
                    acc[mfl][nf] = __builtin_amdgcn_mfma_f32_16x16x32_bf16(
                        af[ks][mfl], bbv, acc[mfl][nf], 0, 0, 0);
            }
        }

        // ---- grouped: 4 tap-pairs (K=32: l4<2 tap a, l4>=2 tap b) ----
        #pragma unroll
        for (int tp = 0; tp < 4; ++tp) {
            const int t8  = tp * 2 + (l4 >> 1);
            const int tap = t8 + (t8 >= 4);
            const int dy  = tap / 3 - 1;
            const int dx  = tap % 3 - 1;
            const int lr  = 1 + dy;                   // slab-local row
            const int oct = r * 2 + (l4 & 1);
            bf16x8 ag[2];
            #pragma unroll
            for (int mfl = 0; mfl < 2; ++mfl) {
                int chunk = r * 64 + p * 16 + tp * 4 + mh * 2 + mfl;
                ag[mfl] = *reinterpret_cast<const bf16x8*>(
                    Wg3 + ((size_t)chunk << 9) + lane * 8);
            }
            #pragma unroll
            for (int nf = 0; nf < 4; ++nf) {
                int c2 = nf * 16 + l15 + dx;
                c2 = ((unsigned)c2 < 64u) ? c2 : 56;   // col 56 is zero pad
                int pix  = lr * 64 + c2;
                int addr = pix * 128 + ((oct ^ (c2 & 7)) << 4);
                bf16x8 bbv = *reinterpret_cast<const bf16x8*>(
                    reinterpret_cast<const char*>(buf) + addr);
                #pragma unroll
                for (int mfl = 0; mfl < 2; ++mfl)
                    acc[mfl][nf] = __builtin_amdgcn_mfma_f32_16x16x32_bf16(
                        ag[mfl], bbv, acc[mfl][nf], 0, 0, 0);
            }
        }

        asm volatile("s_waitcnt vmcnt(0)" ::: "memory");
        __builtin_amdgcn_s_barrier();
    }

    // ---- epilogue: 4 residue-rounds via lf2 (stride 60), f32x4 stores ----
    #pragma unroll
    for (int q = 0; q < 4; ++q) {
        if (r == q) {                     // two waves (mh = 0,1) write halves
            #pragma unroll
            for (int mfl = 0; mfl < 2; ++mfl) {
                #pragma unroll
                for (int j = 0; j < 4; ++j) {
                    int chL = (mh * 2 + mfl) * 16 + l4 * 4 + j;   // [0,64)
                    float bias = bsum[q * 64 + chL];
                    #pragma unroll
                    for (int nf = 0; nf < 4; ++nf) {
                        int col = nf * 16 + l15;
                        if (col < Wd)
                            lf2[chL * 60 + col] = acc[mfl][nf][j] + bias;
                    }
                }
            }
        }
        __syncthreads();
        #pragma unroll
        for (int it = 0; it < 2; ++it) {
            int v = it * 512 + tid;            // 64 chL x 14 float4
            if (v < 896) {
                int chL = v / 14;
                int f   = v % 14;
                int n = (chL << 2) | q;
                f32x4 val = *reinterpret_cast<const f32x4*>(lf2 + chL * 60 + f * 4);
                __builtin_nontemporal_store(val, reinterpret_cast<f32x4*>(
                    y + (((size_t)b * COUT + n) * Hd + row) * Wd + f * 4));
            }
        }
        __syncthreads();
    }
}

extern "C" void kernel_launch(void* const* d_in, const int* in_sizes, int n_in,
                              void* d_out, int out_size, void* d_ws, size_t ws_size,
                              hipStream_t stream) {
    const float* x = (const float*)d_in[0];
    const float* W = (const float*)d_in[1];
    const float* b = (const float*)d_in[2];
    float* y = (float*)d_out;

    unsigned short* Wc3  = (unsigned short*)d_ws;                        // 131072 B
    unsigned short* Wg3  = (unsigned short*)((char*)d_ws + 131072);      // 262144 B
    float*          bsum = (float*)((char*)d_ws + 393216);               // 1024 B
    unsigned short* xb   = (unsigned short*)((char*)d_ws + 394240);      // 60,817,408 B

    hipLaunchKernelGGL(hetconv_prep_all, dim3(1936), dim3(512), 0, stream,
                       x, W, b, xb, Wc3, Wg3, bsum);
    hipLaunchKernelGGL(hetconv_main, dim3(BATCH * 56), dim3(512), 0, stream,
                       xb, Wc3, Wg3, bsum, y);
}

// Round 19
// 111.186 us; speedup vs baseline: 1.1069x; 1.0461x over previous
//
#include <hip/hip_runtime.h>
#include <hip/hip_bf16.h>

#define BATCH 32
#define CIN   256
#define COUT  256
#define Hd    56
#define Wd    56
#define HW    (Hd*Wd)

typedef __attribute__((ext_vector_type(8))) short bf16x8;
typedef __attribute__((ext_vector_type(4))) float f32x4;

typedef const __attribute__((address_space(1))) void* gas1_t;
typedef __attribute__((address_space(3))) void* las3_t;

__device__ __forceinline__ unsigned short f2bf_rne(float f) {
    unsigned u = __builtin_bit_cast(unsigned, f);
    u += 0x7fffu + ((u >> 16) & 1u);
    return (unsigned short)(u >> 16);
}

// ---------------------------------------------------------------------------
// Fused prep (R17/R18-verified, unchanged): [0,1856) xconv | [1856,1904)
// wprep | [1904,1936) bsum.  xb[b][p 4][row 58][col 64][64ch, octet-XOR by
// col&7], residue-interleaved: ic = (p*16+jj)*4+rr for kq = oct*8+e.
// ---------------------------------------------------------------------------
__global__ __launch_bounds__(512) void hetconv_prep_all(const float* __restrict__ x,
                                                        const float* __restrict__ W,
                                                        const float* __restrict__ bb_,
                                                        unsigned short* __restrict__ xb,
                                                        unsigned short* __restrict__ Wc3,
                                                        unsigned short* __restrict__ Wg3,
                                                        float* __restrict__ bsum) {
    const int bid = blockIdx.x;
    const int tid = threadIdx.x;
    const int lane = tid & 63;
    const int wid  = tid >> 6;

    if (bid < 1856) {                    // ---- xconv ----
        const int b  = bid / 58;
        const int pr = bid % 58;
        const int octG = tid >> 4;       // [0,32)
        const int q    = tid & 15;       // col quad; 14,15 write zeros
        const int pass = octG >> 3;
        const int oct  = octG & 7;
        const int grow = pr - 1;
        const bool ok = (grow >= 0) && (grow < Hd) && (q < 14);
        const size_t base = ((size_t)(b * 4 + pass) * 58 + pr) * 4096;
        const float* xrow = x + (size_t)b * CIN * HW + (size_t)grow * Wd + q * 4;

        f32x4 v[8];
        #pragma unroll
        for (int e = 0; e < 8; ++e) {
            int kq = oct * 8 + e;
            int rr = kq >> 4, jj = kq & 15;
            int ic = (pass * 16 + jj) * 4 + rr;
            v[e] = ok ? *reinterpret_cast<const f32x4*>(xrow + (size_t)ic * HW)
                      : f32x4{0.f, 0.f, 0.f, 0.f};
        }
        #pragma unroll
        for (int i = 0; i < 4; ++i) {
            int col = q * 4 + i;
            bf16x8 pk;
            #pragma unroll
            for (int e = 0; e < 8; ++e) pk[e] = (short)f2bf_rne(v[e][i]);
            __builtin_nontemporal_store(pk,
                reinterpret_cast<bf16x8*>(xb + base + col * 64 + ((oct ^ (col & 7)) * 8)));
        }
    } else if (bid < 1904) {             // ---- wprep ----
        const int u = (bid - 1856) * 8 + wid;    // [0,384)
        const int l15 = lane & 15;
        const int l4  = lane >> 4;
        if (u < 128) {                   // Wc: u = r*32+p*8+ks*4+mf
            const int mf = u & 3;
            const int ks = (u >> 2) & 1;
            const int p  = (u >> 3) & 3;
            const int r  = u >> 5;
            const int np = r * 64 + mf * 16 + l15;
            const int n  = ((np & 63) << 2) | r;
            #pragma unroll
            for (int e = 0; e < 8; ++e) {
                int kq = ks * 32 + l4 * 8 + e;
                int rr = kq >> 4, jj = kq & 15;
                int ic = (p * 16 + jj) * 4 + rr;
                Wc3[u * 512 + lane * 8 + e] = f2bf_rne(W[(n * CIN + ic) * 9 + 4]);
            }
        } else {                         // Wg: u2 = r*64+p*16+tp*4+mf
            const int u2 = u - 128;
            const int mf = u2 & 3;
            const int tp = (u2 >> 2) & 3;
            const int p  = (u2 >> 4) & 3;
            const int r  = u2 >> 6;
            const int np = r * 64 + mf * 16 + l15;
            const int n  = ((np & 63) << 2) | r;
            const int t8  = tp * 2 + (l4 >> 1);
            const int tap = t8 + (t8 >= 4);
            #pragma unroll
            for (int e = 0; e < 8; ++e) {
                int jj = (l4 & 1) * 8 + e;
                int ic = (p * 16 + jj) * 4 + r;
                Wg3[u2 * 512 + lane * 8 + e] = f2bf_rne(W[(n * CIN + ic) * 9 + tap]);
            }
        }
    } else {                             // ---- bsum ----
        const int np = (bid - 1904) * 8 + wid;   // [0,256)
        const int n = ((np & 63) << 2) | (np >> 6);
        float s = 0.f;
        for (int i = lane; i < CIN; i += 64) s += bb_[n * CIN + i];
        #pragma unroll
        for (int off = 32; off > 0; off >>= 1) s += __shfl_down(s, off, 64);
        if (lane == 0) bsum[np] = s;
    }
}

// ---------------------------------------------------------------------------
// Main (R16 schedule x R17 layout): 896 blocks (XCD-swizzled) x 1024 threads
// = 16 waves = (h = wid&1, mh = (wid>>1)&1, r = wid>>2); per-wave 32 out-ch
// x 64 cols, acc[2][4] = 32 AGPR + ~56 arch.  Stage ALL FOUR 32 KB pass
// slabs (128 KB LDS), ONE vmcnt(0)+barrier, then 4 passes of {16 dense +
// 32 grouped MFMA per wave} as one unbroken stream (balanced every pass,
// 12x fewer bank conflicts than R16's layout).  2-round epilogue reusing
// slabs 0-1 as 59 KB scratch; nontemporal f32x4 stores.
// ---------------------------------------------------------------------------
__global__ __launch_bounds__(1024, 2) void hetconv_main(const unsigned short* __restrict__ xb,
                             const unsigned short* __restrict__ Wc3,
                             const unsigned short* __restrict__ Wg3,
                             const float* __restrict__ bsum,
                             float* __restrict__ y) {
    __shared__ unsigned short xs[4][16384];   // 4 x 32 KB slabs (epilogue reuses 0-1)

    const int bid  = blockIdx.x;
    const int work = (bid & 7) * 112 + (bid >> 3);   // XCD-contiguous (896 = 8*112)
    const int b    = work / 28;
    const int R0   = (work % 28) * 2;
    const int tid = threadIdx.x;
    const int lane = tid & 63;
    const int wid  = tid >> 6;        // [0,16)
    const int h  = wid & 1;
    const int mh = (wid >> 1) & 1;
    const int r  = wid >> 2;
    const int l15 = lane & 15;
    const int l4  = lane >> 4;

    f32x4 acc[2][4];
    #pragma unroll
    for (int i = 0; i < 2; ++i)
        #pragma unroll
        for (int j = 0; j < 4; ++j) acc[i][j] = f32x4{0.f, 0.f, 0.f, 0.f};

    // ---- stage all four pass slabs (8 x 16B per thread), single drain ----
    #pragma unroll
    for (int p = 0; p < 4; ++p) {
        const unsigned short* slab = xb + ((size_t)(b * 4 + p) * 58 + R0) * 4096;
        #pragma unroll
        for (int rd = 0; rd < 2; ++rd) {
            int vbase = rd * 1024 + wid * 64;     // 16B-unit index, wave-uniform
            __builtin_amdgcn_global_load_lds(
                (gas1_t)(slab + (size_t)(vbase + lane) * 8),
                (las3_t)(xs[p] + vbase * 8), 16, 0, 0);
        }
    }
    asm volatile("s_waitcnt vmcnt(0)" ::: "memory");
    __builtin_amdgcn_s_barrier();

    // ---- 4 passes, one unbroken MFMA stream, balanced every pass ----
    #pragma unroll
    for (int p = 0; p < 4; ++p) {
        const unsigned short* buf = xs[p];
        const int srow = (h + 1) * 64;

        // dense: 2 K-steps of 32 interleaved channels
        #pragma unroll
        for (int ks = 0; ks < 2; ++ks) {
            bf16x8 a[2];
            #pragma unroll
            for (int mfl = 0; mfl < 2; ++mfl) {
                int chunk = r * 32 + p * 8 + ks * 4 + mh * 2 + mfl;
                a[mfl] = *reinterpret_cast<const bf16x8*>(
                    Wc3 + ((size_t)chunk << 9) + lane * 8);
            }
            #pragma unroll
            for (int nf = 0; nf < 4; ++nf) {
                int col = nf * 16 + l15;
                int pix = srow + col;
                int oct = ks * 4 + l4;
                int addr = pix * 128 + ((oct ^ (col & 7)) << 4);
                bf16x8 bbv = *reinterpret_cast<const bf16x8*>(
                    reinterpret_cast<const char*>(buf) + addr);
                #pragma unroll
                for (int mfl = 0; mfl < 2; ++mfl)
                    acc[mfl][nf] = __builtin_amdgcn_mfma_f32_16x16x32_bf16(
                        a[mfl], bbv, acc[mfl][nf], 0, 0, 0);
            }
        }

        // grouped: 4 tap-pairs (K=32: l4>>1 selects tap, l4&1 selects jj-half)
        #pragma unroll
        for (int tp = 0; tp < 4; ++tp) {
            const int t8  = tp * 2 + (l4 >> 1);
            const int tap = t8 + (t8 >= 4);
            const int dy  = tap / 3 - 1;
            const int dx  = tap % 3 - 1;
            const int lr  = h + 1 + dy;
            const int oct = r * 2 + (l4 & 1);
            bf16x8 ag[2];
            #pragma unroll
            for (int mfl = 0; mfl < 2; ++mfl) {
                int chunk = r * 64 + p * 16 + tp * 4 + mh * 2 + mfl;
                ag[mfl] = *reinterpret_cast<const bf16x8*>(
                    Wg3 + ((size_t)chunk << 9) + lane * 8);
            }
            #pragma unroll
            for (int nf = 0; nf < 4; ++nf) {
                int c2 = nf * 16 + l15 + dx;
                c2 = ((unsigned)c2 < 64u) ? c2 : 56;   // col 56 is zero pad
                int pix  = lr * 64 + c2;
                int addr = pix * 128 + ((oct ^ (c2 & 7)) << 4);
                bf16x8 bbv = *reinterpret_cast<const bf16x8*>(
                    reinterpret_cast<const char*>(buf) + addr);
                #pragma unroll
                for (int mfl = 0; mfl < 2; ++mfl)
                    acc[mfl][nf] = __builtin_amdgcn_mfma_f32_16x16x32_bf16(
                        ag[mfl], bbv, acc[mfl][nf], 0, 0, 0);
            }
        }
    }
    __syncthreads();                      // slab reads done; xs reusable

    // ---- epilogue: 2 rounds of 128 channels via xs scratch (R16-proven) ----
    float* lf = reinterpret_cast<float*>(xs[0]);     // 59,392 B <= 2 slabs
    #pragma unroll
    for (int q = 0; q < 2; ++q) {
        if ((r >> 1) == q) {
            #pragma unroll
            for (int mfl = 0; mfl < 2; ++mfl) {
                #pragma unroll
                for (int j = 0; j < 4; ++j) {
                    int chL = (r & 1) * 64 + mh * 32 + mfl * 16 + l4 * 4 + j;
                    float bias = bsum[q * 128 + chL];
                    #pragma unroll
                    for (int nf = 0; nf < 4; ++nf) {
                        int col = nf * 16 + l15;
                        if (col < Wd)
                            lf[chL * 116 + h * 56 + col] = acc[mfl][nf][j] + bias;
                    }
                }
            }
        }
        __syncthreads();
        #pragma unroll
        for (int it = 0; it < 4; ++it) {
            int v = it * 1024 + tid;           // 128 chL x 28 float4
            if (v < 3584) {
                int chL = v / 28;
                int f   = v % 28;
                int h2  = (f >= 14) ? 1 : 0;
                int colS = (f - h2 * 14) * 4;
                int n = ((chL & 63) << 2) | (q * 2 + (chL >> 6));
                f32x4 val = *reinterpret_cast<const f32x4*>(lf + chL * 116 + f * 4);
                __builtin_nontemporal_store(val, reinterpret_cast<f32x4*>(
                    y + (((size_t)b * COUT + n) * Hd + (R0 + h2)) * Wd + colS));
            }
        }
        __syncthreads();
    }
}

extern "C" void kernel_launch(void* const* d_in, const int* in_sizes, int n_in,
                              void* d_out, int out_size, void* d_ws, size_t ws_size,
                              hipStream_t stream) {
    const float* x = (const float*)d_in[0];
    const float* W = (const float*)d_in[1];
    const float* b = (const float*)d_in[2];
    float* y = (float*)d_out;

    unsigned short* Wc3  = (unsigned short*)d_ws;                        // 131072 B
    unsigned short* Wg3  = (unsigned short*)((char*)d_ws + 131072);      // 262144 B
    float*          bsum = (float*)((char*)d_ws + 393216);               // 1024 B
    unsigned short* xb   = (unsigned short*)((char*)d_ws + 394240);      // 60,817,408 B

    hipLaunchKernelGGL(hetconv_prep_all, dim3(1936), dim3(512), 0, stream,
                       x, W, b, xb, Wc3, Wg3, bsum);
    hipLaunchKernelGGL(hetconv_main, dim3(BATCH * 28), dim3(1024), 0, stream,
                       xb, Wc3, Wg3, bsum, y);
}

// Round 20
// 98.205 us; speedup vs baseline: 1.2532x; 1.1322x over previous
//
#include <hip/hip_runtime.h>
#include <hip/hip_bf16.h>

#define BATCH 32
#define CIN   256
#define COUT  256
#define Hd    56
#define Wd    56
#define HW    (Hd*Wd)

typedef __attribute__((ext_vector_type(8))) short bf16x8;
typedef __attribute__((ext_vector_type(4))) float f32x4;

__device__ __forceinline__ unsigned short f2bf_rne(float f) {
    unsigned u = __builtin_bit_cast(unsigned, f);
    u += 0x7fffu + ((u >> 16) & 1u);
    return (unsigned short)(u >> 16);
}

// ---------------------------------------------------------------------------
// Weight prep + bsum (R17/R19-verified, xconv removed): blocks [0,48) wprep,
// [48,80) bsum.  Lane-linear 1 KB chunks, residue-interleaved channel order:
// ic = (p*16+jj)*4+rr.
// ---------------------------------------------------------------------------
__global__ __launch_bounds__(512) void hetconv_wprep(const float* __restrict__ W,
                                                     const float* __restrict__ bb_,
                                                     unsigned short* __restrict__ Wc3,
                                                     unsigned short* __restrict__ Wg3,
                                                     float* __restrict__ bsum) {
    const int bid = blockIdx.x;
    const int tid = threadIdx.x;
    const int lane = tid & 63;
    const int wid  = tid >> 6;

    if (bid < 48) {                      // ---- wprep: 8 chunks per block ----
        const int u = bid * 8 + wid;     // [0,384)
        const int l15 = lane & 15;
        const int l4  = lane >> 4;
        if (u < 128) {                   // Wc: u = r*32+p*8+ks*4+mf
            const int mf = u & 3;
            const int ks = (u >> 2) & 1;
            const int p  = (u >> 3) & 3;
            const int r  = u >> 5;
            const int np = r * 64 + mf * 16 + l15;
            const int n  = ((np & 63) << 2) | r;
            #pragma unroll
            for (int e = 0; e < 8; ++e) {
                int kq = ks * 32 + l4 * 8 + e;
                int rr = kq >> 4, jj = kq & 15;
                int ic = (p * 16 + jj) * 4 + rr;
                Wc3[u * 512 + lane * 8 + e] = f2bf_rne(W[(n * CIN + ic) * 9 + 4]);
            }
        } else {                         // Wg: u2 = r*64+p*16+tp*4+mf
            const int u2 = u - 128;
            const int mf = u2 & 3;
            const int tp = (u2 >> 2) & 3;
            const int p  = (u2 >> 4) & 3;
            const int r  = u2 >> 6;
            const int np = r * 64 + mf * 16 + l15;
            const int n  = ((np & 63) << 2) | r;
            const int t8  = tp * 2 + (l4 >> 1);
            const int tap = t8 + (t8 >= 4);
            #pragma unroll
            for (int e = 0; e < 8; ++e) {
                int jj = (l4 & 1) * 8 + e;
                int ic = (p * 16 + jj) * 4 + r;
                Wg3[u2 * 512 + lane * 8 + e] = f2bf_rne(W[(n * CIN + ic) * 9 + tap]);
            }
        }
    } else {                             // ---- bsum: 8 np per block ----
        const int np = (bid - 48) * 8 + wid;     // [0,256)
        const int n = ((np & 63) << 2) | (np >> 6);
        float s = 0.f;
        for (int i = lane; i < CIN; i += 64) s += bb_[n * CIN + i];
        #pragma unroll
        for (int off = 32; off > 0; off >>= 1) s += __shfl_down(s, off, 64);
        if (lane == 0) bsum[np] = s;
    }
}

// ---------------------------------------------------------------------------
// Fused main: 896 blocks (XCD-swizzled) x 1024 threads = 16 waves =
// (h, mh, r); per-wave 32 out-ch x 64 cols, acc[2][4] = 32 AGPR.
// NO xb: x is read directly (proven xconv load pattern), converted in
// registers, ds_written into the 4 pass slabs with the SAME byte layout the
// verified R19 compute reads.  Conversion phase A (passes 0,1) before one
// barrier; phase B (passes 2,3) between compute(0) and compute(1) — HBM
// latency hides under other waves' MFMA (16 waves, no barrier until
// compute(2) needs slab 2).  Compute + epilogue verbatim R19.
// ---------------------------------------------------------------------------
__global__ __launch_bounds__(1024, 2) void hetconv_main(const float* __restrict__ x,
                             const unsigned short* __restrict__ Wc3,
                             const unsigned short* __restrict__ Wg3,
                             const float* __restrict__ bsum,
                             float* __restrict__ y) {
    __shared__ unsigned short xs[4][16384];   // 4 x 32 KB slabs (epilogue reuses 0-1)

    const int bid  = blockIdx.x;
    const int work = (bid & 7) * 112 + (bid >> 3);   // XCD-contiguous (896 = 8*112)
    const int b    = work / 28;
    const int R0   = (work % 28) * 2;
    const int tid = threadIdx.x;
    const int lane = tid & 63;
    const int wid  = tid >> 6;        // [0,16)
    const int h  = wid & 1;
    const int mh = (wid >> 1) & 1;
    const int r  = wid >> 2;
    const int l15 = lane & 15;
    const int l4  = lane >> 4;

    const float* xbase = x + (size_t)b * CIN * HW;

    f32x4 acc[2][4];
    #pragma unroll
    for (int i = 0; i < 2; ++i)
        #pragma unroll
        for (int j = 0; j < 4; ++j) acc[i][j] = f32x4{0.f, 0.f, 0.f, 0.f};

    // ---- conversion: one 512-assignment cover per pass; lane = [ol2|q4]
    // so 16-lane groups load 256B contiguous; wave spans 4 octs -> 8-way
    // max ds_write conflict with the col&7 XOR (read layout unchanged).
    auto CONVERT = [&](int pass, unsigned short* dst) {
        const int a   = tid & 511;
        const int q   = a & 15;                       // col quad; 14,15 -> zeros
        const int oct = ((a >> 4) & 3) | (((a >> 6) & 1) << 2);
        const int row = (a >> 7) & 3;                 // slab-local row
        const int grow = R0 - 1 + row;
        const bool ok = (grow >= 0) && (grow < Hd) && (q < 14);
        const float* xrow = xbase + (size_t)grow * Wd + q * 4;
        f32x4 v[8];
        #pragma unroll
        for (int e = 0; e < 8; ++e) {
            int kq = oct * 8 + e;
            int rr = kq >> 4, jj = kq & 15;
            int ic = (pass * 16 + jj) * 4 + rr;
            v[e] = ok ? *reinterpret_cast<const f32x4*>(xrow + (size_t)ic * HW)
                      : f32x4{0.f, 0.f, 0.f, 0.f};
        }
        #pragma unroll
        for (int i = 0; i < 4; ++i) {
            int col = q * 4 + i;
            bf16x8 pk;
            #pragma unroll
            for (int e = 0; e < 8; ++e) pk[e] = (short)f2bf_rne(v[e][i]);
            *reinterpret_cast<bf16x8*>(
                reinterpret_cast<char*>(dst) + (row * 64 + col) * 128
                + ((oct ^ (col & 7)) << 4)) = pk;
        }
    };

    // ---- compute one pass (R19 verbatim) ----
    auto COMPUTE = [&](int p) {
        const unsigned short* buf = xs[p];
        const int srow = (h + 1) * 64;
        #pragma unroll
        for (int ks = 0; ks < 2; ++ks) {
            bf16x8 a[2];
            #pragma unroll
            for (int mfl = 0; mfl < 2; ++mfl) {
                int chunk = r * 32 + p * 8 + ks * 4 + mh * 2 + mfl;
                a[mfl] = *reinterpret_cast<const bf16x8*>(
                    Wc3 + ((size_t)chunk << 9) + lane * 8);
            }
            #pragma unroll
            for (int nf = 0; nf < 4; ++nf) {
                int col = nf * 16 + l15;
                int pix = srow + col;
                int oct = ks * 4 + l4;
                int addr = pix * 128 + ((oct ^ (col & 7)) << 4);
                bf16x8 bbv = *reinterpret_cast<const bf16x8*>(
                    reinterpret_cast<const char*>(buf) + addr);
                #pragma unroll
                for (int mfl = 0; mfl < 2; ++mfl)
                    acc[mfl][nf] = __builtin_amdgcn_mfma_f32_16x16x32_bf16(
                        a[mfl], bbv, acc[mfl][nf], 0, 0, 0);
            }
        }
        #pragma unroll
        for (int tp = 0; tp < 4; ++tp) {
            const int t8  = tp * 2 + (l4 >> 1);
            const int tap = t8 + (t8 >= 4);
            const int dy  = tap / 3 - 1;
            const int dx  = tap % 3 - 1;
            const int lr  = h + 1 + dy;
            const int oct = r * 2 + (l4 & 1);
            bf16x8 ag[2];
            #pragma unroll
            for (int mfl = 0; mfl < 2; ++mfl) {
                int chunk = r * 64 + p * 16 + tp * 4 + mh * 2 + mfl;
                ag[mfl] = *reinterpret_cast<const bf16x8*>(
                    Wg3 + ((size_t)chunk << 9) + lane * 8);
            }
            #pragma unroll
            for (int nf = 0; nf < 4; ++nf) {
                int c2 = nf * 16 + l15 + dx;
                c2 = ((unsigned)c2 < 64u) ? c2 : 56;   // col 56 is zero pad
                int pix  = lr * 64 + c2;
                int addr = pix * 128 + ((oct ^ (c2 & 7)) << 4);
                bf16x8 bbv = *reinterpret_cast<const bf16x8*>(
                    reinterpret_cast<const char*>(buf) + addr);
                #pragma unroll
                for (int mfl = 0; mfl < 2; ++mfl)
                    acc[mfl][nf] = __builtin_amdgcn_mfma_f32_16x16x32_bf16(
                        ag[mfl], bbv, acc[mfl][nf], 0, 0, 0);
            }
        }
    };

    // ---- schedule ----
    const int hb = tid >> 9;              // wave-half: 0 or 1
    CONVERT(hb, xs[hb]);                  // phase A: slabs 0,1
    __syncthreads();
    COMPUTE(0);
    CONVERT(2 + hb, xs[2 + hb]);          // phase B: slabs 2,3 (no barrier yet)
    COMPUTE(1);
    __syncthreads();                      // slabs 2,3 ready
    COMPUTE(2);
    COMPUTE(3);
    __syncthreads();                      // slab reads done; xs reusable

    // ---- epilogue (R19 verbatim): 2 rounds via xs scratch ----
    float* lf = reinterpret_cast<float*>(xs[0]);     // 59,392 B <= 2 slabs
    #pragma unroll
    for (int q = 0; q < 2; ++q) {
        if ((r >> 1) == q) {
            #pragma unroll
            for (int mfl = 0; mfl < 2; ++mfl) {
                #pragma unroll
                for (int j = 0; j < 4; ++j) {
                    int chL = (r & 1) * 64 + mh * 32 + mfl * 16 + l4 * 4 + j;
                    float bias = bsum[q * 128 + chL];
                    #pragma unroll
                    for (int nf = 0; nf < 4; ++nf) {
                        int col = nf * 16 + l15;
                        if (col < Wd)
                            lf[chL * 116 + h * 56 + col] = acc[mfl][nf][j] + bias;
                    }
                }
            }
        }
        __syncthreads();
        #pragma unroll
        for (int it = 0; it < 4; ++it) {
            int v = it * 1024 + tid;           // 128 chL x 28 float4
            if (v < 3584) {
                int chL = v / 28;
                int f   = v % 28;
                int h2  = (f >= 14) ? 1 : 0;
                int colS = (f - h2 * 14) * 4;
                int n = ((chL & 63) << 2) | (q * 2 + (chL >> 6));
                f32x4 val = *reinterpret_cast<const f32x4*>(lf + chL * 116 + f * 4);
                __builtin_nontemporal_store(val, reinterpret_cast<f32x4*>(
                    y + (((size_t)b * COUT + n) * Hd + (R0 + h2)) * Wd + colS));
            }
        }
        __syncthreads();
    }
}

extern "C" void kernel_launch(void* const* d_in, const int* in_sizes, int n_in,
                              void* d_out, int out_size, void* d_ws, size_t ws_size,
                              hipStream_t stream) {
    const float* x = (const float*)d_in[0];
    const float* W = (const float*)d_in[1];
    const float* b = (const float*)d_in[2];
    float* y = (float*)d_out;

    unsigned short* Wc3  = (unsigned short*)d_ws;                        // 131072 B
    unsigned short* Wg3  = (unsigned short*)((char*)d_ws + 131072);      // 262144 B
    float*          bsum = (float*)((char*)d_ws + 393216);               // 1024 B

    hipLaunchKernelGGL(hetconv_wprep, dim3(80), dim3(512), 0, stream,
                       W, b, Wc3, Wg3, bsum);
    hipLaunchKernelGGL(hetconv_main, dim3(BATCH * 28), dim3(1024), 0, stream,
                       x, Wc3, Wg3, bsum, y);
}

// Round 21
// 91.290 us; speedup vs baseline: 1.3481x; 1.0757x over previous
//
#include <hip/hip_runtime.h>
#include <hip/hip_bf16.h>

#define BATCH 32
#define CIN   256
#define COUT  256
#define Hd    56
#define Wd    56
#define HW    (Hd*Wd)

typedef __attribute__((ext_vector_type(8))) short bf16x8;
typedef __attribute__((ext_vector_type(4))) short bf16x4;
typedef __attribute__((ext_vector_type(4))) float f32x4;

__device__ __forceinline__ unsigned short f2bf_rne(float f) {
    unsigned u = __builtin_bit_cast(unsigned, f);
    u += 0x7fffu + ((u >> 16) & 1u);
    return (unsigned short)(u >> 16);
}

// ---------------------------------------------------------------------------
// Weight prep + bsum (R20-verified): blocks [0,48) wprep, [48,80) bsum.
// Lane-linear 1 KB chunks, residue-interleaved: ic = (p*16+jj)*4+rr.
// ---------------------------------------------------------------------------
__global__ __launch_bounds__(512) void hetconv_wprep(const float* __restrict__ W,
                                                     const float* __restrict__ bb_,
                                                     unsigned short* __restrict__ Wc3,
                                                     unsigned short* __restrict__ Wg3,
                                                     float* __restrict__ bsum) {
    const int bid = blockIdx.x;
    const int tid = threadIdx.x;
    const int lane = tid & 63;
    const int wid  = tid >> 6;

    if (bid < 48) {                      // ---- wprep: 8 chunks per block ----
        const int u = bid * 8 + wid;     // [0,384)
        const int l15 = lane & 15;
        const int l4  = lane >> 4;
        if (u < 128) {                   // Wc: u = r*32+p*8+ks*4+mf
            const int mf = u & 3;
            const int ks = (u >> 2) & 1;
            const int p  = (u >> 3) & 3;
            const int r  = u >> 5;
            const int np = r * 64 + mf * 16 + l15;
            const int n  = ((np & 63) << 2) | r;
            #pragma unroll
            for (int e = 0; e < 8; ++e) {
                int kq = ks * 32 + l4 * 8 + e;
                int rr = kq >> 4, jj = kq & 15;
                int ic = (p * 16 + jj) * 4 + rr;
                Wc3[u * 512 + lane * 8 + e] = f2bf_rne(W[(n * CIN + ic) * 9 + 4]);
            }
        } else {                         // Wg: u2 = r*64+p*16+tp*4+mf
            const int u2 = u - 128;
            const int mf = u2 & 3;
            const int tp = (u2 >> 2) & 3;
            const int p  = (u2 >> 4) & 3;
            const int r  = u2 >> 6;
            const int np = r * 64 + mf * 16 + l15;
            const int n  = ((np & 63) << 2) | r;
            const int t8  = tp * 2 + (l4 >> 1);
            const int tap = t8 + (t8 >= 4);
            #pragma unroll
            for (int e = 0; e < 8; ++e) {
                int jj = (l4 & 1) * 8 + e;
                int ic = (p * 16 + jj) * 4 + r;
                Wg3[u2 * 512 + lane * 8 + e] = f2bf_rne(W[(n * CIN + ic) * 9 + tap]);
            }
        }
    } else {                             // ---- bsum: 8 np per block ----
        const int np = (bid - 48) * 8 + wid;     // [0,256)
        const int n = ((np & 63) << 2) | (np >> 6);
        float s = 0.f;
        for (int i = lane; i < CIN; i += 64) s += bb_[n * CIN + i];
        #pragma unroll
        for (int off = 32; off > 0; off >>= 1) s += __shfl_down(s, off, 64);
        if (lane == 0) bsum[np] = s;
    }
}

// ---------------------------------------------------------------------------
// Fused main (R20 structure; CONVERT register footprint halved to kill the
// spill): 896 blocks (XCD-swizzled) x 1024 threads = 16 waves = (h, mh, r);
// per-wave 32 out-ch x 64 cols, acc[2][4] = 32 AGPR.  x read directly,
// converted in TWO halves of 4 channels (v[4] live = 16 VGPRs), ds_written
// as 8B half-slots into the same slab byte layout the verified R19/R20
// compute reads.  Compute + epilogue verbatim.
// ---------------------------------------------------------------------------
__global__ __launch_bounds__(1024, 2) void hetconv_main(const float* __restrict__ x,
                             const unsigned short* __restrict__ Wc3,
                             const unsigned short* __restrict__ Wg3,
                             const float* __restrict__ bsum,
                             float* __restrict__ y) {
    __shared__ unsigned short xs[4][16384];   // 4 x 32 KB slabs (epilogue reuses 0-1)

    const int bid  = blockIdx.x;
    const int work = (bid & 7) * 112 + (bid >> 3);   // XCD-contiguous (896 = 8*112)
    const int b    = work / 28;
    const int R0   = (work % 28) * 2;
    const int tid = threadIdx.x;
    const int lane = tid & 63;
    const int wid  = tid >> 6;        // [0,16)
    const int h  = wid & 1;
    const int mh = (wid >> 1) & 1;
    const int r  = wid >> 2;
    const int l15 = lane & 15;
    const int l4  = lane >> 4;

    const float* xbase = x + (size_t)b * CIN * HW;

    f32x4 acc[2][4];
    #pragma unroll
    for (int i = 0; i < 2; ++i)
        #pragma unroll
        for (int j = 0; j < 4; ++j) acc[i][j] = f32x4{0.f, 0.f, 0.f, 0.f};

    // ---- conversion: 512-assignment cover per pass; lane = [row2|ol2|q4];
    // two halves of 4 channels each -> only 16 VGPRs of x-data live.
    auto CONVERT = [&](int pass, unsigned short* dst) {
        const int a   = tid & 511;
        const int q   = a & 15;                       // col quad; 14,15 -> zeros
        const int oct = ((a >> 4) & 3) | (((a >> 6) & 1) << 2);
        const int row = (a >> 7) & 3;                 // slab-local row
        const int grow = R0 - 1 + row;
        const bool ok = (grow >= 0) && (grow < Hd) && (q < 14);
        const float* xrow = xbase + (size_t)grow * Wd + q * 4;
        #pragma unroll
        for (int hf = 0; hf < 2; ++hf) {
            f32x4 v[4];
            #pragma unroll
            for (int e4 = 0; e4 < 4; ++e4) {
                int kq = oct * 8 + hf * 4 + e4;
                int rr = kq >> 4, jj = kq & 15;
                int ic = (pass * 16 + jj) * 4 + rr;
                v[e4] = ok ? *reinterpret_cast<const f32x4*>(xrow + (size_t)ic * HW)
                           : f32x4{0.f, 0.f, 0.f, 0.f};
            }
            #pragma unroll
            for (int i = 0; i < 4; ++i) {
                int col = q * 4 + i;
                bf16x4 pk;
                #pragma unroll
                for (int e4 = 0; e4 < 4; ++e4) pk[e4] = (short)f2bf_rne(v[e4][i]);
                *reinterpret_cast<bf16x4*>(
                    reinterpret_cast<char*>(dst) + (row * 64 + col) * 128
                    + ((oct ^ (col & 7)) << 4) + hf * 8) = pk;
            }
        }
    };

    // ---- compute one pass (R19/R20 verbatim) ----
    auto COMPUTE = [&](int p) {
        const unsigned short* buf = xs[p];
        const int srow = (h + 1) * 64;
        #pragma unroll
        for (int ks = 0; ks < 2; ++ks) {
            bf16x8 a[2];
            #pragma unroll
            for (int mfl = 0; mfl < 2; ++mfl) {
                int chunk = r * 32 + p * 8 + ks * 4 + mh * 2 + mfl;
                a[mfl] = *reinterpret_cast<const bf16x8*>(
                    Wc3 + ((size_t)chunk << 9) + lane * 8);
            }
            #pragma unroll
            for (int nf = 0; nf < 4; ++nf) {
                int col = nf * 16 + l15;
                int pix = srow + col;
                int oct = ks * 4 + l4;
                int addr = pix * 128 + ((oct ^ (col & 7)) << 4);
                bf16x8 bbv = *reinterpret_cast<const bf16x8*>(
                    reinterpret_cast<const char*>(buf) + addr);
                #pragma unroll
                for (int mfl = 0; mfl < 2; ++mfl)
                    acc[mfl][nf] = __builtin_amdgcn_mfma_f32_16x16x32_bf16(
                        a[mfl], bbv, acc[mfl][nf], 0, 0, 0);
            }
        }
        #pragma unroll
        for (int tp = 0; tp < 4; ++tp) {
            const int t8  = tp * 2 + (l4 >> 1);
            const int tap = t8 + (t8 >= 4);
            const int dy  = tap / 3 - 1;
            const int dx  = tap % 3 - 1;
            const int lr  = h + 1 + dy;
            const int oct = r * 2 + (l4 & 1);
            bf16x8 ag[2];
            #pragma unroll
            for (int mfl = 0; mfl < 2; ++mfl) {
                int chunk = r * 64 + p * 16 + tp * 4 + mh * 2 + mfl;
                ag[mfl] = *reinterpret_cast<const bf16x8*>(
                    Wg3 + ((size_t)chunk << 9) + lane * 8);
            }
            #pragma unroll
            for (int nf = 0; nf < 4; ++nf) {
                int c2 = nf * 16 + l15 + dx;
                c2 = ((unsigned)c2 < 64u) ? c2 : 56;   // col 56 is zero pad
                int pix  = lr * 64 + c2;
                int addr = pix * 128 + ((oct ^ (c2 & 7)) << 4);
                bf16x8 bbv = *reinterpret_cast<const bf16x8*>(
                    reinterpret_cast<const char*>(buf) + addr);
                #pragma unroll
                for (int mfl = 0; mfl < 2; ++mfl)
                    acc[mfl][nf] = __builtin_amdgcn_mfma_f32_16x16x32_bf16(
                        ag[mfl], bbv, acc[mfl][nf], 0, 0, 0);
            }
        }
    };

    // ---- schedule (R20-proven) ----
    const int hb = tid >> 9;              // wave-half: 0 or 1
    CONVERT(hb, xs[hb]);                  // phase A: slabs 0,1
    __syncthreads();
    COMPUTE(0);
    CONVERT(2 + hb, xs[2 + hb]);          // phase B: slabs 2,3 (no barrier yet)
    COMPUTE(1);
    __syncthreads();                      // slabs 2,3 ready
    COMPUTE(2);
    COMPUTE(3);
    __syncthreads();                      // slab reads done; xs reusable

    // ---- epilogue (verbatim): 2 rounds via xs scratch ----
    float* lf = reinterpret_cast<float*>(xs[0]);     // 59,392 B <= 2 slabs
    #pragma unroll
    for (int q = 0; q < 2; ++q) {
        if ((r >> 1) == q) {
            #pragma unroll
            for (int mfl = 0; mfl < 2; ++mfl) {
                #pragma unroll
                for (int j = 0; j < 4; ++j) {
                    int chL = (r & 1) * 64 + mh * 32 + mfl * 16 + l4 * 4 + j;
                    float bias = bsum[q * 128 + chL];
                    #pragma unroll
                    for (int nf = 0; nf < 4; ++nf) {
                        int col = nf * 16 + l15;
                        if (col < Wd)
                            lf[chL * 116 + h * 56 + col] = acc[mfl][nf][j] + bias;
                    }
                }
            }
        }
        __syncthreads();
        #pragma unroll
        for (int it = 0; it < 4; ++it) {
            int v = it * 1024 + tid;           // 128 chL x 28 float4
            if (v < 3584) {
                int chL = v / 28;
                int f   = v % 28;
                int h2  = (f >= 14) ? 1 : 0;
                int colS = (f - h2 * 14) * 4;
                int n = ((chL & 63) << 2) | (q * 2 + (chL >> 6));
                f32x4 val = *reinterpret_cast<const f32x4*>(lf + chL * 116 + f * 4);
                __builtin_nontemporal_store(val, reinterpret_cast<f32x4*>(
                    y + (((size_t)b * COUT + n) * Hd + (R0 + h2)) * Wd + colS));
            }
        }
        __syncthreads();
    }
}

extern "C" void kernel_launch(void* const* d_in, const int* in_sizes, int n_in,
                              void* d_out, int out_size, void* d_ws, size_t ws_size,
                              hipStream_t stream) {
    const float* x = (const float*)d_in[0];
    const float* W = (const float*)d_in[1];
    const float* b = (const float*)d_in[2];
    float* y = (float*)d_out;

    unsigned short* Wc3  = (unsigned short*)d_ws;                        // 131072 B
    unsigned short* Wg3  = (unsigned short*)((char*)d_ws + 131072);      // 262144 B
    float*          bsum = (float*)((char*)d_ws + 393216);               // 1024 B

    hipLaunchKernelGGL(hetconv_wprep, dim3(80), dim3(512), 0, stream,
                       W, b, Wc3, Wg3, bsum);
    hipLaunchKernelGGL(hetconv_main, dim3(BATCH * 28), dim3(1024), 0, stream,
                       x, Wc3, Wg3, bsum, y);
}